// Round 11
// baseline (1338.894 us; speedup 1.0000x reference)
//
#include <hip/hip_runtime.h>
#include <hip/hip_cooperative_groups.h>

namespace cg = cooperative_groups;

#define NN 100000
#define NE 1600000
#define NG 128
#define BN_EPS 1e-5f
#define NBKT 64
#define NBUCK 98          // ceil(NN / 1024)
#define BIN_BLOCKS 256
#define BIN_CHUNK 6250    // NE / BIN_BLOCKS exact
#define POOL_CHUNKS 1563  // ceil(NN / 64)

typedef short s16x8 __attribute__((ext_vector_type(8)));
typedef float f32x4 __attribute__((ext_vector_type(4)));

static __device__ __forceinline__ unsigned short f2bf(float f) {
    unsigned u = __float_as_uint(f);
    u += 0x7fffu + ((u >> 16) & 1u);   // RNE
    return (unsigned short)(u >> 16);
}
static __device__ __forceinline__ unsigned packbf(float a, float b) {
    return (unsigned)f2bf(a) | ((unsigned)f2bf(b) << 16);
}
static __device__ __forceinline__ float bf_lo(unsigned u) { return __uint_as_float(u << 16); }
static __device__ __forceinline__ float bf_hi(unsigned u) { return __uint_as_float(u & 0xffff0000u); }
static __device__ __forceinline__ float bf2f(ushort u) { return __uint_as_float((unsigned)u << 16); }

// ================= device phase bodies (shared by coop + fallback kernels) =================

__device__ __forceinline__ void dev_bhist(const int* __restrict__ dst, int* __restrict__ gbh,
                                          int* lh, int b, int nb, int t) {
    if (t < 128) lh[t] = 0;
    __syncthreads();
    for (int e = b * 256 + t; e < NE; e += nb * 256) atomicAdd(&lh[dst[e] >> 10], 1);
    __syncthreads();
    if (t < 128 && lh[t]) atomicAdd(&gbh[t], lh[t]);
}

__device__ __forceinline__ void dev_bscan(const int* __restrict__ gbh, int* __restrict__ gbase,
                                          int* __restrict__ gcur, int* __restrict__ row_start,
                                          int* sbuf, int t) {
    int v = (t < 128) ? gbh[t] : 0;
    sbuf[t] = v;
    __syncthreads();
    for (int o = 1; o < 128; o <<= 1) {
        int a = (t >= o && t < 128) ? sbuf[t - o] : 0;
        __syncthreads();
        sbuf[t] += a;
        __syncthreads();
    }
    if (t < 128) {
        int ex = sbuf[t] - v;
        gbase[t] = ex;
        gcur[t] = ex;
        if (t == 127) { gbase[128] = sbuf[127]; row_start[NN] = NE; }
    }
}

__device__ __forceinline__ void dev_bin(const int* __restrict__ src, const int* __restrict__ dst,
                                        int* __restrict__ gcur, int* __restrict__ tmp,
                                        int* lh, int* lb, int* lc, int chunk, int t) {
    if (t < 128) lh[t] = 0;
    __syncthreads();
    int e0 = chunk * BIN_CHUNK, e1 = e0 + BIN_CHUNK;
    for (int e = e0 + t; e < e1; e += 256) atomicAdd(&lh[dst[e] >> 10], 1);
    __syncthreads();
    if (t < 128) {
        int c = lh[t];
        lb[t] = c ? atomicAdd(&gcur[t], c) : 0;
        lc[t] = 0;
    }
    __syncthreads();
    for (int e = e0 + t; e < e1; e += 256) {
        int d = dst[e];
        int bb = d >> 10;
        int off = atomicAdd(&lc[bb], 1);
        tmp[lb[bb] + off] = (src[e] << 10) | (d & 1023);
    }
    __syncthreads();
}

__device__ __forceinline__ void dev_csr(const int* __restrict__ tmp, const int* __restrict__ gbase,
                                        int* __restrict__ esrc, int* __restrict__ row_start,
                                        float* __restrict__ dinv, int* h, int* hs, int* part,
                                        int bk, int t) {
    int base = gbase[bk], end = gbase[bk + 1];
#pragma unroll
    for (int k = 0; k < 4; ++k) h[t * 4 + k] = 0;
    __syncthreads();
    for (int i = base + t; i < end; i += 256) atomicAdd(&h[tmp[i] & 1023], 1);
    __syncthreads();
    int l0 = h[t * 4], l1 = h[t * 4 + 1], l2 = h[t * 4 + 2], l3 = h[t * 4 + 3];
    int ssum = l0 + l1 + l2 + l3;
    part[t] = ssum;
    __syncthreads();
    for (int o = 1; o < 256; o <<= 1) {
        int a = (t >= o) ? part[t - o] : 0;
        __syncthreads();
        part[t] += a;
        __syncthreads();
    }
    int ex = part[t] - ssum;
    hs[t * 4]     = ex;
    hs[t * 4 + 1] = ex + l0;
    hs[t * 4 + 2] = ex + l0 + l1;
    hs[t * 4 + 3] = ex + l0 + l1 + l2;
    int n0 = bk * 1024 + t * 4;
#pragma unroll
    for (int k = 0; k < 4; ++k) {
        int n = n0 + k;
        if (n < NN) {
            row_start[n] = base + hs[t * 4 + k];
            dinv[n] = rsqrtf((float)h[t * 4 + k] + 1.0f);
        }
    }
    __syncthreads();
    for (int i = base + t; i < end; i += 256) {
        int rec = tmp[i];
        int pos = atomicAdd(&hs[rec & 1023], 1);
        esrc[base + pos] = rec >> 10;
    }
    __syncthreads();
}

__device__ __forceinline__ void dev_wfrag(const float* __restrict__ W, ushort* __restrict__ Wfl,
                                          int unit, int t) {
    if (t >= 64) return;
    int ks = unit >> 3, nb = unit & 7;
    int n = nb * 16 + (t & 15);
    int k0 = ks * 32 + (t >> 4) * 8;
    ushort o[8];
#pragma unroll
    for (int j = 0; j < 8; ++j) o[j] = f2bf(W[(size_t)(k0 + j) * 128 + n]);
    ushort* p = Wfl + ((size_t)unit * 64 + t) * 8;
#pragma unroll
    for (int j = 0; j < 8; ++j) p[j] = o[j];
}

__device__ __forceinline__ void dev_agg(const uint* __restrict__ hm32, const int* __restrict__ esrc,
                                        const int* __restrict__ rs, const float* __restrict__ dinv,
                                        const float* __restrict__ bias, uint* __restrict__ act,
                                        float* __restrict__ bnsum, float* __restrict__ bnsq,
                                        float* ls, float* lq, int tid, int wgid, int nwaves, int bkt) {
    if (tid < 128) { ls[tid] = 0.f; lq[tid] = 0.f; }
    __syncthreads();
    int lane = tid & 63;
    float2 b2 = *(const float2*)(bias + lane * 2);
    float s0 = 0.f, s1 = 0.f, q0 = 0.f, q1 = 0.f;

    for (int n = wgid; n < NN; n += nwaves) {
        uint self = hm32[(size_t)n * 64 + lane];
        float a0 = bf_lo(self);
        float a1 = bf_hi(self);

        int i  = __builtin_amdgcn_readfirstlane(rs[n]);
        int i1 = __builtin_amdgcn_readfirstlane(rs[n + 1]);

        int idxv = 0;
        if (i < i1) idxv = esrc[i + min(min(lane, 15), i1 - i - 1)];

        while (i < i1) {
            int cnt = i1 - i;
            cnt = (cnt > 16) ? 16 : cnt;       // wave-uniform
            int cur = idxv;
            int inext = i + cnt;
            if (inext < i1)                    // prefetch next chunk while gathers fly
                idxv = esrc[inext + min(min(lane, 15), i1 - inext - 1)];
            uint g[16];
#pragma unroll
            for (int u = 0; u < 16; ++u) {
                int sidx = __builtin_amdgcn_readlane(cur, u);
                sidx = (u < cnt) ? sidx : NN;  // pads -> zero row
                g[u] = hm32[(size_t)sidx * 64 + lane];
            }
#pragma unroll
            for (int u = 0; u < 16; ++u) {
                a0 += bf_lo(g[u]);
                a1 += bf_hi(g[u]);
            }
            i = inext;
        }
        float di = dinv[n];
        float z0 = fmaxf(fmaf(di, a0, b2.x), 0.f);
        float z1 = fmaxf(fmaf(di, a1, b2.y), 0.f);
        act[(size_t)n * 64 + lane] = packbf(z0, z1);
        s0 += z0; s1 += z1;
        q0 += z0 * z0; q1 += z1 * z1;
    }
    atomicAdd(&ls[lane * 2],     s0);
    atomicAdd(&ls[lane * 2 + 1], s1);
    atomicAdd(&lq[lane * 2],     q0);
    atomicAdd(&lq[lane * 2 + 1], q1);
    __syncthreads();
    if (tid < 128) {
        atomicAdd(&bnsum[bkt * 128 + tid], ls[tid]);
        atomicAdd(&bnsq[bkt * 128 + tid],  lq[tid]);
    }
}

__device__ __forceinline__ void dev_finw(const float* __restrict__ S, const float* __restrict__ Q,
                                         const float* __restrict__ gam, const float* __restrict__ bet,
                                         float* __restrict__ svec, float* __restrict__ tvec,
                                         const float* __restrict__ Wnext, float* __restrict__ tW,
                                         const ushort* __restrict__ Wfb, ushort* __restrict__ Wff,
                                         float* ts, float* svl, int b, int t) {
    if (b == 0) {
        if (t < 128) {
            float s = 0.f, q = 0.f;
            for (int k = 0; k < NBKT; ++k) {
                s += S[k * 128 + t];
                q += Q[k * 128 + t];
            }
            float mean = s / (float)NN;
            float var = q / (float)NN - mean * mean;
            float rstd = rsqrtf(fmaxf(var, 0.f) + BN_EPS);
            float sc = gam[t] * rstd;
            float sh = bet[t] - mean * sc;
            svec[t] = sc;
            tvec[t] = sh;
            ts[t] = sh;
        }
        __syncthreads();
        if (Wnext && t < 128) {
            float acc = 0.f;
            for (int k = 0; k < 128; ++k) acc += ts[k] * Wnext[(size_t)k * 128 + t];
            tW[t] = acc;
        }
    } else if (b <= 32 && Wfb) {
        int unit = b - 1;
        int kbase = (unit >> 3) * 32;
        if (t < 32) {
            int c = kbase + t;
            float s = 0.f, q = 0.f;
            for (int k = 0; k < NBKT; ++k) {
                s += S[k * 128 + c];
                q += Q[k * 128 + c];
            }
            float mean = s / (float)NN;
            float var = q / (float)NN - mean * mean;
            svl[t] = gam[c] * rsqrtf(fmaxf(var, 0.f) + BN_EPS);
        }
        __syncthreads();
        if (t < 64) {
            int ko = (t >> 4) * 8;
            const ushort* p = Wfb + ((size_t)unit * 64 + t) * 8;
            ushort* o = Wff + ((size_t)unit * 64 + t) * 8;
#pragma unroll
            for (int j = 0; j < 8; ++j) o[j] = f2bf(bf2f(p[j]) * svl[ko + j]);
        }
    }
}

__device__ __forceinline__ void dev_pool(const uint* __restrict__ act32, const float* __restrict__ svec,
                                         const float* __restrict__ tvec, const int* __restrict__ batch,
                                         float* __restrict__ gout, float* __restrict__ outp, int lofs,
                                         int nb0, int nbstride, int tid) {
    int lane = tid & 63;
    int w = tid >> 6;
    float sc0 = svec[lane * 2], sc1 = svec[lane * 2 + 1];
    float sh0 = tvec[lane * 2], sh1 = tvec[lane * 2 + 1];
    for (int nb = nb0; nb < POOL_CHUNKS; nb += nbstride) {
        int n0 = nb * 64;
        float s0 = 0.f, s1 = 0.f;
        int cnt = 0, curg = -1;
        for (int k = w; k < 64; k += 4) {
            int n = n0 + k;
            if (n >= NN) break;
            int gn = batch[n];
            if (gn != curg) {
                if (cnt) {
                    atomicAdd(&gout[(size_t)curg * 384 + lofs + lane * 2],     sc0 * s0 + sh0 * (float)cnt);
                    atomicAdd(&gout[(size_t)curg * 384 + lofs + lane * 2 + 1], sc1 * s1 + sh1 * (float)cnt);
                }
                curg = gn; s0 = 0.f; s1 = 0.f; cnt = 0;
            }
            uint v = act32[(size_t)n * 64 + lane];
            float a0 = bf_lo(v), a1 = bf_hi(v);
            float2 z;
            z.x = a0 * sc0 + sh0;
            z.y = a1 * sc1 + sh1;
            *(float2*)(outp + (size_t)n * 384 + lofs + lane * 2) = z;
            s0 += a0;
            s1 += a1;
            ++cnt;
        }
        if (cnt) {
            atomicAdd(&gout[(size_t)curg * 384 + lofs + lane * 2],     sc0 * s0 + sh0 * (float)cnt);
            atomicAdd(&gout[(size_t)curg * 384 + lofs + lane * 2 + 1], sc1 * s1 + sh1 * (float)cnt);
        }
    }
}

// ================= cooperative mega-kernels =================

__global__ __launch_bounds__(256) void k_build(const float* __restrict__ W0, const float* __restrict__ W1,
                                               const float* __restrict__ W2, const int* __restrict__ src,
                                               const int* __restrict__ dst, ushort* __restrict__ Wf,
                                               int* __restrict__ gbh, int* __restrict__ gbase,
                                               int* __restrict__ gcur, int* __restrict__ row_start,
                                               int* __restrict__ tmp, int* __restrict__ esrc,
                                               float* __restrict__ dinv, float* __restrict__ bnst,
                                               float* __restrict__ gout, uint* __restrict__ hmz) {
    cg::grid_group grid = cg::this_grid();
    __shared__ int lh[128], lb[128], lc[128];
    __shared__ int h[1024], hs[1024], part[256];
    int t = threadIdx.x, b = blockIdx.x;
    int nb = gridDim.x;

    // phase 0: wfrag (blocks 0..95) + zero gbh/bnst/gout/zero-row (blocks 96..)
    if (b < 96) {
        int layer = b >> 5, unit = b & 31;
        const float* W = (layer == 0) ? W0 : ((layer == 1) ? W1 : W2);
        dev_wfrag(W, Wf + (size_t)layer * 16384, unit, t);
    } else {
        int gid = (b - 96) * 256 + t;
        if (gid < 128) gbh[gid] = 0;
        else if (gid < 49280) bnst[gid - 128] = 0.f;
        else if (gid < 98432) gout[gid - 49280] = 0.f;
        else if (gid < 98496) hmz[gid - 98432] = 0u;
    }
    grid.sync();
    // phase 1: coarse histogram
    dev_bhist(dst, gbh, lh, b, nb, t);
    grid.sync();
    // phase 2: bucket scan (block 0)
    if (b == 0) dev_bscan(gbh, gbase, gcur, row_start, part, t);
    grid.sync();
    // phase 3: bin edges
    for (int c = b; c < BIN_BLOCKS; c += nb) dev_bin(src, dst, gcur, tmp, lh, lb, lc, c, t);
    grid.sync();
    // phase 4: per-bucket counting sort
    for (int bk = b; bk < NBUCK; bk += nb) dev_csr(tmp, gbase, esrc, row_start, dinv, h, hs, part, bk, t);
}

__global__ __launch_bounds__(256) void k_layer(const uint* __restrict__ hm32, const int* __restrict__ esrc,
                                               const int* __restrict__ rs, const float* __restrict__ dinv,
                                               const float* __restrict__ bias, uint* __restrict__ act,
                                               float* __restrict__ S, float* __restrict__ Q,
                                               const float* __restrict__ gam, const float* __restrict__ bet,
                                               float* __restrict__ svec, float* __restrict__ tvec,
                                               const float* __restrict__ Wnext, float* __restrict__ tW,
                                               const ushort* __restrict__ Wfb, ushort* __restrict__ Wff,
                                               const int* __restrict__ batch, float* __restrict__ gout,
                                               float* __restrict__ outp, int lofs) {
    cg::grid_group grid = cg::this_grid();
    __shared__ float ls[128], lq[128];
    __shared__ float ts[128], svl[32];
    int tid = threadIdx.x;
    int wgid = blockIdx.x * 4 + (tid >> 6);
    dev_agg(hm32, esrc, rs, dinv, bias, act, S, Q, ls, lq, tid, wgid, gridDim.x * 4,
            blockIdx.x & (NBKT - 1));
    grid.sync();
    dev_finw(S, Q, gam, bet, svec, tvec, Wnext, tW, Wfb, Wff, ts, svl, blockIdx.x, tid);
    grid.sync();
    dev_pool(act, svec, tvec, batch, gout, outp, lofs, blockIdx.x, gridDim.x, tid);
}

// ================= standalone fallback kernels =================

__global__ __launch_bounds__(256) void k_bhist(const int* __restrict__ dst, int* __restrict__ gbh) {
    __shared__ int lh[128];
    dev_bhist(dst, gbh, lh, blockIdx.x, gridDim.x, threadIdx.x);
}
__global__ __launch_bounds__(256) void k_bscan(const int* __restrict__ gbh, int* __restrict__ gbase,
                                               int* __restrict__ gcur, int* __restrict__ row_start) {
    __shared__ int sbuf[256];
    dev_bscan(gbh, gbase, gcur, row_start, sbuf, threadIdx.x);
}
__global__ __launch_bounds__(256) void k_bin(const int* __restrict__ src, const int* __restrict__ dst,
                                             int* __restrict__ gcur, int* __restrict__ tmp) {
    __shared__ int lh[128], lb[128], lc[128];
    dev_bin(src, dst, gcur, tmp, lh, lb, lc, blockIdx.x, threadIdx.x);
}
__global__ __launch_bounds__(256) void k_csr(const int* __restrict__ tmp, const int* __restrict__ gbase,
                                             int* __restrict__ esrc, int* __restrict__ row_start,
                                             float* __restrict__ dinv) {
    __shared__ int h[1024], hs[1024], part[256];
    dev_csr(tmp, gbase, esrc, row_start, dinv, h, hs, part, blockIdx.x, threadIdx.x);
}
__global__ __launch_bounds__(256) void k_wfrag(const float* __restrict__ W0, const float* __restrict__ W1,
                                               const float* __restrict__ W2, ushort* __restrict__ Wf) {
    int layer = blockIdx.x >> 5;
    const float* W = (layer == 0) ? W0 : ((layer == 1) ? W1 : W2);
    dev_wfrag(W, Wf + (size_t)layer * 16384, blockIdx.x & 31, threadIdx.x);
}
__global__ __launch_bounds__(256) void k_agg(const uint* __restrict__ hm32, const int* __restrict__ esrc,
                                             const int* __restrict__ rs, const float* __restrict__ dinv,
                                             const float* __restrict__ bias, uint* __restrict__ act,
                                             float* __restrict__ bnsum, float* __restrict__ bnsq) {
    __shared__ float ls[128], lq[128];
    int tid = threadIdx.x;
    dev_agg(hm32, esrc, rs, dinv, bias, act, bnsum, bnsq, ls, lq, tid,
            blockIdx.x * 4 + (tid >> 6), gridDim.x * 4, blockIdx.x & (NBKT - 1));
}
__global__ __launch_bounds__(256) void k_finwscale(const float* __restrict__ S, const float* __restrict__ Q,
                                                   const float* __restrict__ gam, const float* __restrict__ bet,
                                                   float* __restrict__ svec, float* __restrict__ tvec,
                                                   const float* __restrict__ Wnext, float* __restrict__ tW,
                                                   const ushort* __restrict__ Wfb, ushort* __restrict__ Wff) {
    __shared__ float ts[128], svl[32];
    dev_finw(S, Q, gam, bet, svec, tvec, Wnext, tW, Wfb, Wff, ts, svl, blockIdx.x, threadIdx.x);
}
__global__ __launch_bounds__(256) void k_pool(const uint* __restrict__ act32, const float* __restrict__ svec,
                                              const float* __restrict__ tvec, const int* __restrict__ batch,
                                              float* __restrict__ gout, float* __restrict__ outp, int lofs) {
    dev_pool(act32, svec, tvec, batch, gout, outp, lofs, blockIdx.x, gridDim.x, threadIdx.x);
}

// ================= MFMA GEMM (normal launch) =================
__global__ __launch_bounds__(256) void k_gemm(const ushort* __restrict__ Xb, const float* __restrict__ xf32,
                                              const ushort* __restrict__ Wf, const float* __restrict__ tW,
                                              const float* __restrict__ dinv, ushort* __restrict__ hm) {
    int tid = threadIdx.x;
    int wid = tid >> 6, lane = tid & 63;
    int r0 = blockIdx.x * 64 + wid * 16;
    int m = lane & 15, g = lane >> 4;
    int xrow = r0 + m;
    int xr = (xrow < NN) ? xrow : (NN - 1);
    s16x8 af[4];
    if (xf32) {
        const float* Xr = xf32 + (size_t)xr * 128 + g * 8;
#pragma unroll
        for (int ks = 0; ks < 4; ++ks) {
            float4 a = *(const float4*)(Xr + ks * 32);
            float4 b = *(const float4*)(Xr + ks * 32 + 4);
            s16x8 v;
            v[0] = (short)f2bf(a.x); v[1] = (short)f2bf(a.y);
            v[2] = (short)f2bf(a.z); v[3] = (short)f2bf(a.w);
            v[4] = (short)f2bf(b.x); v[5] = (short)f2bf(b.y);
            v[6] = (short)f2bf(b.z); v[7] = (short)f2bf(b.w);
            af[ks] = v;
        }
    } else {
        const ushort* Xrow = Xb + (size_t)xr * 128 + g * 8;
#pragma unroll
        for (int ks = 0; ks < 4; ++ks) af[ks] = *(const s16x8*)(Xrow + ks * 32);
    }
    f32x4 acc[8];
#pragma unroll
    for (int nb = 0; nb < 8; ++nb) acc[nb] = (f32x4){0.f, 0.f, 0.f, 0.f};
#pragma unroll
    for (int ks = 0; ks < 4; ++ks) {
#pragma unroll
        for (int nb = 0; nb < 8; ++nb) {
            s16x8 wf = *(const s16x8*)(Wf + ((size_t)(ks * 8 + nb) * 64 + lane) * 8);
            acc[nb] = __builtin_amdgcn_mfma_f32_16x16x32_bf16(wf, af[ks], acc[nb], 0, 0, 0);
        }
    }
    if (xrow < NN) {
        float ds = dinv[xr];
        ushort* orow = hm + (size_t)xrow * 128 + g * 4;
        if (tW) {
#pragma unroll
            for (int nb = 0; nb < 8; ++nb) {
                float4 tw = *(const float4*)(tW + nb * 16 + g * 4);
                ushort4 o;
                o.x = f2bf(ds * (acc[nb][0] + tw.x));
                o.y = f2bf(ds * (acc[nb][1] + tw.y));
                o.z = f2bf(ds * (acc[nb][2] + tw.z));
                o.w = f2bf(ds * (acc[nb][3] + tw.w));
                *(ushort4*)(orow + nb * 16) = o;
            }
        } else {
#pragma unroll
            for (int nb = 0; nb < 8; ++nb) {
                ushort4 o;
                o.x = f2bf(ds * acc[nb][0]);
                o.y = f2bf(ds * acc[nb][1]);
                o.z = f2bf(ds * acc[nb][2]);
                o.w = f2bf(ds * acc[nb][3]);
                *(ushort4*)(orow + nb * 16) = o;
            }
        }
    }
}

extern "C" void kernel_launch(void* const* d_in, const int* in_sizes, int n_in,
                              void* d_out, int out_size, void* d_ws, size_t ws_size,
                              hipStream_t stream) {
    const float* x = (const float*)d_in[0];
    const int* ei = (const int*)d_in[1];
    const int* src = ei;
    const int* dst = ei + NE;
    const int* batch = (const int*)d_in[2];
    const float *W[3], *b[3], *g[3], *beta[3];
    for (int l = 0; l < 3; ++l) {
        W[l]    = (const float*)d_in[3 + 4 * l];
        b[l]    = (const float*)d_in[4 + 4 * l];
        g[l]    = (const float*)d_in[5 + 4 * l];
        beta[l] = (const float*)d_in[6 + 4 * l];
    }
    float* out = (float*)d_out;
    float* gout = out + (size_t)NN * 384;

    char* ws = (char*)d_ws;
    size_t off = 0;
    auto alloc = [&](size_t bytes) -> char* {
        off = (off + 255) & ~(size_t)255;
        char* p = ws + off;
        off += bytes;
        return p;
    };
    ushort* act      = (ushort*)alloc((size_t)NN * 256);
    ushort* hm       = (ushort*)alloc((size_t)(NN + 1) * 256);  // + zero row at NN
    int*    esrc     = (int*)alloc((size_t)NE * 4);
    int*    tmp      = (int*)alloc((size_t)NE * 4);
    int*    row_start= (int*)alloc((size_t)(NN + 1) * 4);
    float*  dinv     = (float*)alloc((size_t)NN * 4);
    float*  bnst     = (float*)alloc((size_t)3 * 2 * NBKT * 128 * 4);
    ushort* Wf       = (ushort*)alloc(3 * 16384 * 2);
    ushort* Wff      = (ushort*)alloc(16384 * 2);
    float*  svt      = (float*)alloc(3 * 2 * 128 * 4);
    float*  tW       = (float*)alloc(128 * 4);
    int*    misc     = (int*)alloc(512 * 4);   // gbh[128], gbase[129], gcur[128]
    int* gbh   = misc;
    int* gbase = misc + 128;
    int* gcur  = misc + 384;
    uint* hmz  = (uint*)(hm + (size_t)NN * 128);
    (void)ws_size;

    // ---- CSR build + setup: one cooperative launch (fallback: standalone chain) ----
    {
        const float* w0 = W[0]; const float* w1 = W[1]; const float* w2 = W[2];
        const int* sp = src; const int* dp = dst;
        ushort* wfp = Wf; int* gbhp = gbh; int* gbasep = gbase; int* gcurp = gcur;
        int* rsp = row_start; int* tmpp = tmp; int* esp = esrc; float* dvp = dinv;
        float* bnp = bnst; float* gop = gout; uint* hzp = hmz;
        void* a1[] = {&w0, &w1, &w2, &sp, &dp, &wfp, &gbhp, &gbasep, &gcurp,
                      &rsp, &tmpp, &esp, &dvp, &bnp, &gop, &hzp};
        hipError_t e1 = hipLaunchCooperativeKernel((void*)k_build, dim3(512), dim3(256), a1, 0, stream);
        if (e1 != hipSuccess) {
            hipMemsetAsync(gbh, 0, 128 * 4, stream);
            hipMemsetAsync(hmz, 0, 256, stream);
            hipMemsetAsync(bnst, 0, (size_t)3 * 2 * NBKT * 128 * 4, stream);
            hipMemsetAsync(gout, 0, (size_t)NG * 384 * 4, stream);
            k_bhist<<<512, 256, 0, stream>>>(dst, gbh);
            k_bscan<<<1, 256, 0, stream>>>(gbh, gbase, gcur, row_start);
            k_bin<<<BIN_BLOCKS, 256, 0, stream>>>(src, dst, gcur, tmp);
            k_csr<<<NBUCK, 256, 0, stream>>>(tmp, gbase, esrc, row_start, dinv);
            k_wfrag<<<96, 256, 0, stream>>>(W[0], W[1], W[2], Wf);
        }
    }

    // cooperative grid size for k_layer from occupancy (deterministic)
    int maxb = 0;
    if (hipOccupancyMaxActiveBlocksPerMultiprocessor(&maxb, k_layer, 256, 0) != hipSuccess || maxb < 1)
        maxb = 4;
    int grid2 = maxb * 256;
    if (grid2 > 2048) grid2 = 2048;
    if (grid2 < 256) grid2 = 256;

    for (int l = 0; l < 3; ++l) {
        float* S = bnst + (size_t)l * 2 * NBKT * 128;
        float* Q = S + NBKT * 128;
        float* sv = svt + l * 256;
        float* tv = sv + 128;
        const ushort* gin = (l == 0) ? (const ushort*)nullptr : act;
        const float* xin = (l == 0) ? x : nullptr;
        const ushort* wfrag = (l == 0) ? (Wf + 0) : Wff;
        const float* tw_in = (l == 0) ? nullptr : tW;

        k_gemm<<<(NN + 63) / 64, 256, 0, stream>>>(gin, xin, wfrag, tw_in, dinv, hm);

        const uint* hmp = (const uint*)hm;
        const int* esp = esrc;
        const int* rsp = row_start;
        const float* dvp = dinv;
        const float* bp = b[l];
        uint* actp = (uint*)act;
        float* Sp = S; float* Qp = Q;
        const float* gp = g[l]; const float* bep = beta[l];
        float* svp = sv; float* tvp = tv;
        const float* wnp = (l < 2) ? W[l + 1] : nullptr;
        float* twp = tW;
        const ushort* wfbp = (l < 2) ? (Wf + (size_t)(l + 1) * 16384) : nullptr;
        ushort* wffp = Wff;
        const int* bap = batch;
        float* gop = gout;
        float* outp = out;
        int lofs = l * 128;
        void* a2[] = {&hmp, &esp, &rsp, &dvp, &bp, &actp, &Sp, &Qp, &gp, &bep,
                      &svp, &tvp, &wnp, &twp, &wfbp, &wffp, &bap, &gop, &outp, &lofs};
        hipError_t e2 = hipLaunchCooperativeKernel((void*)k_layer, dim3(grid2), dim3(256), a2, 0, stream);
        if (e2 != hipSuccess) {
            k_agg<<<2048, 256, 0, stream>>>(hmp, esrc, row_start, dinv, b[l], (uint*)act, S, Q);
            k_finwscale<<<(l < 2) ? 33 : 1, 256, 0, stream>>>(S, Q, g[l], beta[l], sv, tv,
                                                              wnp, tW, wfbp, Wff);
            k_pool<<<POOL_CHUNKS, 256, 0, stream>>>((const uint*)act, sv, tv, batch, gout, out, lofs);
        }
    }
}

// Round 12
// 989.632 us; speedup vs baseline: 1.3529x; 1.3529x over previous
//
#include <hip/hip_runtime.h>

#define NN 100000
#define NE 1600000
#define NG 128
#define BN_EPS 1e-5f
#define NBKT 64
#define AGG_BLOCKS 2048
#define AGG_WAVES (AGG_BLOCKS * 4)
#define NBUCK 98          // ceil(NN / 1024)
#define BIN_BLOCKS 256
#define BIN_CHUNK 6250    // NE / BIN_BLOCKS exact

typedef short s16x8 __attribute__((ext_vector_type(8)));
typedef float f32x4 __attribute__((ext_vector_type(4)));

static __device__ __forceinline__ unsigned short f2bf(float f) {
    unsigned u = __float_as_uint(f);
    u += 0x7fffu + ((u >> 16) & 1u);   // RNE
    return (unsigned short)(u >> 16);
}
static __device__ __forceinline__ unsigned packbf(float a, float b) {
    return (unsigned)f2bf(a) | ((unsigned)f2bf(b) << 16);
}
static __device__ __forceinline__ float bf_lo(unsigned u) { return __uint_as_float(u << 16); }
static __device__ __forceinline__ float bf_hi(unsigned u) { return __uint_as_float(u & 0xffff0000u); }
static __device__ __forceinline__ float bf2f(ushort u) { return __uint_as_float((unsigned)u << 16); }

// ---------------- setup: W fragments + all zeroing (replaces 4 memsets + wfrag) ----------------
__global__ __launch_bounds__(256) void k_setup(const float* __restrict__ W0, const float* __restrict__ W1,
                                               const float* __restrict__ W2, ushort* __restrict__ Wf,
                                               int* __restrict__ gbh, int* __restrict__ ticks,
                                               float* __restrict__ bnst, float* __restrict__ gout,
                                               uint* __restrict__ hmz) {
    int b = blockIdx.x, t = threadIdx.x;
    if (b < 96) {
        if (t >= 64) return;
        int layer = b >> 5, unit = b & 31;
        const float* W = (layer == 0) ? W0 : ((layer == 1) ? W1 : W2);
        int ks = unit >> 3, nb = unit & 7;
        int n = nb * 16 + (t & 15);
        int k0 = ks * 32 + (t >> 4) * 8;
        ushort o[8];
#pragma unroll
        for (int j = 0; j < 8; ++j) o[j] = f2bf(W[(size_t)(k0 + j) * 128 + n]);
        ushort* p = Wf + (size_t)layer * 16384 + ((size_t)unit * 64 + t) * 8;
#pragma unroll
        for (int j = 0; j < 8; ++j) p[j] = o[j];
    } else {
        int gid = (b - 96) * 256 + t;
        if (gid < 49152) bnst[gid] = 0.f;
        else if (gid < 98304) gout[gid - 49152] = 0.f;
        else if (gid < 98432) gbh[gid - 98304] = 0;
        else if (gid < 98440) ticks[gid - 98432] = 0;
        else if (gid < 98504) hmz[gid - 98440] = 0u;
    }
}

// ---------------- coarse bucket histogram + fused scan (last-block ticket) ----------------
__global__ __launch_bounds__(256) void k_bhist(const int* __restrict__ dst, int* __restrict__ gbh,
                                               int* __restrict__ gbase, int* __restrict__ gcur,
                                               int* __restrict__ row_start, int* __restrict__ tick) {
    __shared__ int lh[128], sbuf[128];
    __shared__ int isLast;
    int t = threadIdx.x;
    if (t < 128) lh[t] = 0;
    __syncthreads();
    for (int e = blockIdx.x * 256 + t; e < NE; e += gridDim.x * 256)
        atomicAdd(&lh[dst[e] >> 10], 1);
    __syncthreads();
    if (t < 128 && lh[t]) atomicAdd(&gbh[t], lh[t]);
    __threadfence();
    __syncthreads();
    if (t == 0) isLast = (atomicAdd(tick, 1) == (int)gridDim.x - 1);
    __syncthreads();
    if (!isLast) return;
    // last block: exclusive scan of the 128 bucket counts
    int v = 0;
    if (t < 128) { v = atomicAdd(&gbh[t], 0); sbuf[t] = v; }
    __syncthreads();
    for (int o = 1; o < 128; o <<= 1) {
        int a = (t >= o && t < 128) ? sbuf[t - o] : 0;
        __syncthreads();
        if (t < 128) sbuf[t] += a;
        __syncthreads();
    }
    if (t < 128) {
        int ex = sbuf[t] - v;
        gbase[t] = ex;
        gcur[t] = ex;
        if (t == 127) { gbase[128] = sbuf[127]; row_start[NN] = NE; }
    }
}

// ---------------- pass 1: bin edges into bucket regions (time-dense writes) ----------------
__global__ __launch_bounds__(256) void k_bin(const int* __restrict__ src, const int* __restrict__ dst,
                                             int* __restrict__ gcur, int* __restrict__ tmp) {
    __shared__ int lh[128], lb[128], lc[128];
    int t = threadIdx.x;
    if (t < 128) lh[t] = 0;
    __syncthreads();
    int e0 = blockIdx.x * BIN_CHUNK, e1 = e0 + BIN_CHUNK;
    for (int e = e0 + t; e < e1; e += 256) atomicAdd(&lh[dst[e] >> 10], 1);
    __syncthreads();
    if (t < 128) {
        int c = lh[t];
        lb[t] = c ? atomicAdd(&gcur[t], c) : 0;
        lc[t] = 0;
    }
    __syncthreads();
    for (int e = e0 + t; e < e1; e += 256) {
        int d = dst[e];
        int b = d >> 10;
        int off = atomicAdd(&lc[b], 1);
        tmp[lb[b] + off] = (src[e] << 10) | (d & 1023);   // src:17b | dst_lo:10b
    }
}

// ---------------- pass 2: per-bucket counting sort -> esrc, row_start, dinv ----------------
__global__ __launch_bounds__(256) void k_csr(const int* __restrict__ tmp, const int* __restrict__ gbase,
                                             int* __restrict__ esrc, int* __restrict__ row_start,
                                             float* __restrict__ dinv) {
    __shared__ int h[1024], hs[1024], part[256];
    int b = blockIdx.x, t = threadIdx.x;
    int base = gbase[b], end = gbase[b + 1];
#pragma unroll
    for (int k = 0; k < 4; ++k) h[t * 4 + k] = 0;
    __syncthreads();
    for (int i = base + t; i < end; i += 256) atomicAdd(&h[tmp[i] & 1023], 1);
    __syncthreads();
    int l0 = h[t * 4], l1 = h[t * 4 + 1], l2 = h[t * 4 + 2], l3 = h[t * 4 + 3];
    int ssum = l0 + l1 + l2 + l3;
    part[t] = ssum;
    __syncthreads();
    for (int o = 1; o < 256; o <<= 1) {
        int a = (t >= o) ? part[t - o] : 0;
        __syncthreads();
        part[t] += a;
        __syncthreads();
    }
    int ex = part[t] - ssum;
    hs[t * 4]     = ex;
    hs[t * 4 + 1] = ex + l0;
    hs[t * 4 + 2] = ex + l0 + l1;
    hs[t * 4 + 3] = ex + l0 + l1 + l2;
    int n0 = b * 1024 + t * 4;
#pragma unroll
    for (int k = 0; k < 4; ++k) {
        int n = n0 + k;
        if (n < NN) {
            row_start[n] = base + hs[t * 4 + k];
            dinv[n] = rsqrtf((float)h[t * 4 + k] + 1.0f);
        }
    }
    __syncthreads();
    for (int i = base + t; i < end; i += 256) {
        int rec = tmp[i];
        int pos = atomicAdd(&hs[rec & 1023], 1);
        esrc[base + pos] = rec >> 10;
    }
}

// ---------------- MFMA GEMM (pure): hm'[N][128] = dinv[row] * (X @ Wf + tW) ----------------
__global__ __launch_bounds__(256) void k_gemm(const ushort* __restrict__ Xb, const float* __restrict__ xf32,
                                              const ushort* __restrict__ Wf, const float* __restrict__ tW,
                                              const float* __restrict__ dinv, ushort* __restrict__ hm) {
    int tid = threadIdx.x;
    int wid = tid >> 6, lane = tid & 63;
    int r0 = blockIdx.x * 64 + wid * 16;
    int m = lane & 15, g = lane >> 4;
    int xrow = r0 + m;
    int xr = (xrow < NN) ? xrow : (NN - 1);
    s16x8 af[4];
    if (xf32) {
        const float* Xr = xf32 + (size_t)xr * 128 + g * 8;
#pragma unroll
        for (int ks = 0; ks < 4; ++ks) {
            float4 a = *(const float4*)(Xr + ks * 32);
            float4 b = *(const float4*)(Xr + ks * 32 + 4);
            s16x8 v;
            v[0] = (short)f2bf(a.x); v[1] = (short)f2bf(a.y);
            v[2] = (short)f2bf(a.z); v[3] = (short)f2bf(a.w);
            v[4] = (short)f2bf(b.x); v[5] = (short)f2bf(b.y);
            v[6] = (short)f2bf(b.z); v[7] = (short)f2bf(b.w);
            af[ks] = v;
        }
    } else {
        const ushort* Xrow = Xb + (size_t)xr * 128 + g * 8;
#pragma unroll
        for (int ks = 0; ks < 4; ++ks) af[ks] = *(const s16x8*)(Xrow + ks * 32);
    }
    f32x4 acc[8];
#pragma unroll
    for (int nb = 0; nb < 8; ++nb) acc[nb] = (f32x4){0.f, 0.f, 0.f, 0.f};
#pragma unroll
    for (int ks = 0; ks < 4; ++ks) {
#pragma unroll
        for (int nb = 0; nb < 8; ++nb) {
            s16x8 wf = *(const s16x8*)(Wf + ((size_t)(ks * 8 + nb) * 64 + lane) * 8);
            acc[nb] = __builtin_amdgcn_mfma_f32_16x16x32_bf16(wf, af[ks], acc[nb], 0, 0, 0);
        }
    }
    if (xrow < NN) {
        float ds = dinv[xr];
        ushort* orow = hm + (size_t)xrow * 128 + g * 4;
        if (tW) {
#pragma unroll
            for (int nb = 0; nb < 8; ++nb) {
                float4 tw = *(const float4*)(tW + nb * 16 + g * 4);
                ushort4 o;
                o.x = f2bf(ds * (acc[nb][0] + tw.x));
                o.y = f2bf(ds * (acc[nb][1] + tw.y));
                o.z = f2bf(ds * (acc[nb][2] + tw.z));
                o.w = f2bf(ds * (acc[nb][3] + tw.w));
                *(ushort4*)(orow + nb * 16) = o;
            }
        } else {
#pragma unroll
            for (int nb = 0; nb < 8; ++nb) {
                ushort4 o;
                o.x = f2bf(ds * acc[nb][0]);
                o.y = f2bf(ds * acc[nb][1]);
                o.z = f2bf(ds * acc[nb][2]);
                o.w = f2bf(ds * acc[nb][3]);
                *(ushort4*)(orow + nb * 16) = o;
            }
        }
    }
}

// ---------------- aggregate + bias + relu + BN stats + fused finalize/wscale epilogue ----------------
__global__ __launch_bounds__(256) void k_agg(const uint* __restrict__ hm32, const int* __restrict__ esrc,
                                             const int* __restrict__ rs, const float* __restrict__ dinv,
                                             const float* __restrict__ bias, uint* __restrict__ act,
                                             float* __restrict__ bnsum, float* __restrict__ bnsq,
                                             const float* __restrict__ gam, const float* __restrict__ bet,
                                             float* __restrict__ svec, float* __restrict__ tvec,
                                             const float* __restrict__ Wnext, float* __restrict__ tW,
                                             const ushort* __restrict__ Wfb, ushort* __restrict__ Wff,
                                             int* __restrict__ tick) {
    __shared__ float ls[128], lq[128];
    __shared__ int isLast;
    int tid = threadIdx.x;
    if (tid < 128) { ls[tid] = 0.f; lq[tid] = 0.f; }
    __syncthreads();
    int lane = tid & 63;
    int wgid = blockIdx.x * 4 + (tid >> 6);
    float2 b2 = *(const float2*)(bias + lane * 2);
    float s0 = 0.f, s1 = 0.f, q0 = 0.f, q1 = 0.f;

    for (int n = wgid; n < NN; n += AGG_WAVES) {
        uint self = hm32[(size_t)n * 64 + lane];
        float a0 = bf_lo(self);
        float a1 = bf_hi(self);

        int i  = __builtin_amdgcn_readfirstlane(rs[n]);
        int i1 = __builtin_amdgcn_readfirstlane(rs[n + 1]);

        int idxv = 0;
        if (i < i1) idxv = esrc[i + min(min(lane, 15), i1 - i - 1)];

        while (i < i1) {
            int cnt = i1 - i;
            cnt = (cnt > 16) ? 16 : cnt;       // wave-uniform
            int cur = idxv;
            int inext = i + cnt;
            if (inext < i1)                    // prefetch next chunk while gathers fly
                idxv = esrc[inext + min(min(lane, 15), i1 - inext - 1)];
            uint g[16];
#pragma unroll
            for (int u = 0; u < 16; ++u) {
                int sidx = __builtin_amdgcn_readlane(cur, u);
                sidx = (u < cnt) ? sidx : NN;  // pads -> zero row
                g[u] = hm32[(size_t)sidx * 64 + lane];
            }
#pragma unroll
            for (int u = 0; u < 16; ++u) {
                a0 += bf_lo(g[u]);
                a1 += bf_hi(g[u]);
            }
            i = inext;
        }
        float di = dinv[n];
        float z0 = fmaxf(fmaf(di, a0, b2.x), 0.f);
        float z1 = fmaxf(fmaf(di, a1, b2.y), 0.f);
        act[(size_t)n * 64 + lane] = packbf(z0, z1);
        s0 += z0; s1 += z1;
        q0 += z0 * z0; q1 += z1 * z1;
    }
    atomicAdd(&ls[lane * 2],     s0);
    atomicAdd(&ls[lane * 2 + 1], s1);
    atomicAdd(&lq[lane * 2],     q0);
    atomicAdd(&lq[lane * 2 + 1], q1);
    __syncthreads();
    if (tid < 128) {
        int bkt = blockIdx.x & (NBKT - 1);
        atomicAdd(&bnsum[bkt * 128 + tid], ls[tid]);
        atomicAdd(&bnsq[bkt * 128 + tid],  lq[tid]);
    }
    __threadfence();
    __syncthreads();
    if (tid == 0) isLast = (atomicAdd(tick, 1) == (int)gridDim.x - 1);
    __syncthreads();
    if (!isLast) return;

    // ---- last block: BN finalize (+ tW, Wff scale for next layer) ----
    {
        int ch = tid & 127, half = tid >> 7;
        float s = 0.f, q = 0.f;
#pragma unroll 8
        for (int k = half * 32; k < half * 32 + 32; ++k) {
            s += atomicAdd(&bnsum[k * 128 + ch], 0.f);   // atomic read: cross-XCD-safe
            q += atomicAdd(&bnsq[k * 128 + ch], 0.f);
        }
        __syncthreads();
        if (half) { ls[ch] = s; lq[ch] = q; }
        __syncthreads();
        if (!half) {
            s += ls[ch]; q += lq[ch];
            float mean = s / (float)NN;
            float var = q / (float)NN - mean * mean;
            float rstd = rsqrtf(fmaxf(var, 0.f) + BN_EPS);
            float sc = gam[ch] * rstd;
            float sh = bet[ch] - mean * sc;
            svec[ch] = sc;
            tvec[ch] = sh;
            ls[ch] = sc;   // LDS now holds scale
            lq[ch] = sh;   // and shift
        }
        __syncthreads();
        if (Wnext) {
            if (tid < 128) {
                float acc = 0.f;
#pragma unroll 8
                for (int k = 0; k < 128; ++k) acc += lq[k] * Wnext[(size_t)k * 128 + tid];
                tW[tid] = acc;
            }
            for (int p = tid; p < 2048; p += 256) {
                int unit = p >> 6, ln = p & 63;
                int k0 = (unit >> 3) * 32 + ((ln >> 4) & 3) * 8;
                const ushort* pp = Wfb + ((size_t)unit * 64 + ln) * 8;
                ushort* oo = Wff + ((size_t)unit * 64 + ln) * 8;
#pragma unroll
                for (int j = 0; j < 8; ++j) oo[j] = f2bf(bf2f(pp[j]) * ls[k0 + j]);
            }
        }
    }
}

// ---------------- per-graph pool + h_cat out-write ----------------
__global__ __launch_bounds__(128) void k_pool(const uint* __restrict__ act32, const float* __restrict__ svec,
                                              const float* __restrict__ tvec, const int* __restrict__ batch,
                                              float* __restrict__ gout, float* __restrict__ outp, int lofs) {
    int t = threadIdx.x;
    int lane = t & 63;
    int w = t >> 6;
    int n0 = blockIdx.x * 64;
    float sc0 = svec[lane * 2], sc1 = svec[lane * 2 + 1];
    float sh0 = tvec[lane * 2], sh1 = tvec[lane * 2 + 1];
    float s0 = 0.f, s1 = 0.f;
    int cnt = 0, curg = -1;
    for (int k = w; k < 64; k += 2) {
        int n = n0 + k;
        if (n >= NN) break;
        int gn = batch[n];
        if (gn != curg) {
            if (cnt) {
                atomicAdd(&gout[(size_t)curg * 384 + lofs + lane * 2],     sc0 * s0 + sh0 * (float)cnt);
                atomicAdd(&gout[(size_t)curg * 384 + lofs + lane * 2 + 1], sc1 * s1 + sh1 * (float)cnt);
            }
            curg = gn; s0 = 0.f; s1 = 0.f; cnt = 0;
        }
        uint v = act32[(size_t)n * 64 + lane];
        float a0 = bf_lo(v), a1 = bf_hi(v);
        float2 z;
        z.x = a0 * sc0 + sh0;
        z.y = a1 * sc1 + sh1;
        *(float2*)(outp + (size_t)n * 384 + lofs + lane * 2) = z;
        s0 += a0;
        s1 += a1;
        ++cnt;
    }
    if (cnt) {
        atomicAdd(&gout[(size_t)curg * 384 + lofs + lane * 2],     sc0 * s0 + sh0 * (float)cnt);
        atomicAdd(&gout[(size_t)curg * 384 + lofs + lane * 2 + 1], sc1 * s1 + sh1 * (float)cnt);
    }
}

extern "C" void kernel_launch(void* const* d_in, const int* in_sizes, int n_in,
                              void* d_out, int out_size, void* d_ws, size_t ws_size,
                              hipStream_t stream) {
    const float* x = (const float*)d_in[0];
    const int* ei = (const int*)d_in[1];
    const int* src = ei;
    const int* dst = ei + NE;
    const int* batch = (const int*)d_in[2];
    const float *W[3], *b[3], *g[3], *beta[3];
    for (int l = 0; l < 3; ++l) {
        W[l]    = (const float*)d_in[3 + 4 * l];
        b[l]    = (const float*)d_in[4 + 4 * l];
        g[l]    = (const float*)d_in[5 + 4 * l];
        beta[l] = (const float*)d_in[6 + 4 * l];
    }
    float* out = (float*)d_out;
    float* gout = out + (size_t)NN * 384;

    char* ws = (char*)d_ws;
    size_t off = 0;
    auto alloc = [&](size_t bytes) -> char* {
        off = (off + 255) & ~(size_t)255;
        char* p = ws + off;
        off += bytes;
        return p;
    };
    ushort* act      = (ushort*)alloc((size_t)NN * 256);        // bf16 relu output (pre-BN)
    ushort* hm       = (ushort*)alloc((size_t)(NN + 1) * 256);  // bf16 hm' rows + zero row at NN
    int*    esrc     = (int*)alloc((size_t)NE * 4);
    int*    tmp      = (int*)alloc((size_t)NE * 4);
    int*    row_start= (int*)alloc((size_t)(NN + 1) * 4);
    float*  dinv     = (float*)alloc((size_t)NN * 4);
    float*  bnst     = (float*)alloc((size_t)3 * 2 * NBKT * 128 * 4);   // [layer][sum|sq][NBKT][128]
    ushort* Wf       = (ushort*)alloc(3 * 16384 * 2);
    ushort* Wff      = (ushort*)alloc(16384 * 2);
    float*  svt      = (float*)alloc(3 * 2 * 128 * 4);                  // [layer][s|t][128]
    float*  tW       = (float*)alloc(128 * 4);
    int*    misc     = (int*)alloc(1024 * 4);   // gbh[128], gbase[129], gcur[128], ticks[8]
    int* gbh   = misc;
    int* gbase = misc + 128;
    int* gcur  = misc + 384;
    int* ticks = misc + 512;
    uint* hmz  = (uint*)(hm + (size_t)NN * 128);
    (void)ws_size;

    // 13 dispatches total, no memsets
    k_setup<<<481, 256, 0, stream>>>(W[0], W[1], W[2], Wf, gbh, ticks, bnst, gout, hmz);
    k_bhist<<<512, 256, 0, stream>>>(dst, gbh, gbase, gcur, row_start, ticks);
    k_bin<<<BIN_BLOCKS, 256, 0, stream>>>(src, dst, gcur, tmp);
    k_csr<<<NBUCK, 256, 0, stream>>>(tmp, gbase, esrc, row_start, dinv);

    for (int l = 0; l < 3; ++l) {
        float* S = bnst + (size_t)l * 2 * NBKT * 128;
        float* Q = S + NBKT * 128;
        float* sv = svt + l * 256;
        float* tv = sv + 128;
        const ushort* gin = (l == 0) ? (const ushort*)nullptr : act;
        const float* xin = (l == 0) ? x : nullptr;
        const ushort* wfrag = (l == 0) ? (Wf + 0) : Wff;
        const float* tw_in = (l == 0) ? nullptr : tW;
        const float* wnp = (l < 2) ? W[l + 1] : nullptr;
        const ushort* wfbp = (l < 2) ? (Wf + (size_t)(l + 1) * 16384) : nullptr;

        k_gemm<<<(NN + 63) / 64, 256, 0, stream>>>(gin, xin, wfrag, tw_in, dinv, hm);
        k_agg<<<AGG_BLOCKS, 256, 0, stream>>>((const uint*)hm, esrc, row_start, dinv, b[l],
                                              (uint*)act, S, Q, g[l], beta[l], sv, tv,
                                              wnp, tW, wfbp, Wff, ticks + 1 + l);
        k_pool<<<(NN + 63) / 64, 128, 0, stream>>>((const uint*)act, sv, tv, batch, gout, out, l * 128);
    }
}

// Round 13
// 474.236 us; speedup vs baseline: 2.8233x; 2.0868x over previous
//
#include <hip/hip_runtime.h>

#define NN 100000
#define NE 1600000
#define NG 128
#define BN_EPS 1e-5f
#define NBKT 64
#define AGG_BLOCKS 2048
#define AGG_WAVES (AGG_BLOCKS * 4)
#define NBUCK 98          // ceil(NN / 1024)
#define BIN_BLOCKS 256
#define BIN_CHUNK 6250    // NE / BIN_BLOCKS exact

typedef short s16x8 __attribute__((ext_vector_type(8)));
typedef float f32x4 __attribute__((ext_vector_type(4)));

static __device__ __forceinline__ unsigned short f2bf(float f) {
    unsigned u = __float_as_uint(f);
    u += 0x7fffu + ((u >> 16) & 1u);   // RNE
    return (unsigned short)(u >> 16);
}
static __device__ __forceinline__ unsigned packbf(float a, float b) {
    return (unsigned)f2bf(a) | ((unsigned)f2bf(b) << 16);
}
static __device__ __forceinline__ float bf_lo(unsigned u) { return __uint_as_float(u << 16); }
static __device__ __forceinline__ float bf_hi(unsigned u) { return __uint_as_float(u & 0xffff0000u); }
static __device__ __forceinline__ float bf2f(ushort u) { return __uint_as_float((unsigned)u << 16); }

// ---------------- setup: W fragments + all zeroing (replaces 4 memsets + wfrag) ----------------
__global__ __launch_bounds__(256) void k_setup(const float* __restrict__ W0, const float* __restrict__ W1,
                                               const float* __restrict__ W2, ushort* __restrict__ Wf,
                                               int* __restrict__ gbh, int* __restrict__ ticks,
                                               float* __restrict__ bnst, float* __restrict__ gout,
                                               uint* __restrict__ hmz) {
    int b = blockIdx.x, t = threadIdx.x;
    if (b < 96) {
        if (t >= 64) return;
        int layer = b >> 5, unit = b & 31;
        const float* W = (layer == 0) ? W0 : ((layer == 1) ? W1 : W2);
        int ks = unit >> 3, nb = unit & 7;
        int n = nb * 16 + (t & 15);
        int k0 = ks * 32 + (t >> 4) * 8;
        ushort o[8];
#pragma unroll
        for (int j = 0; j < 8; ++j) o[j] = f2bf(W[(size_t)(k0 + j) * 128 + n]);
        ushort* p = Wf + (size_t)layer * 16384 + ((size_t)unit * 64 + t) * 8;
#pragma unroll
        for (int j = 0; j < 8; ++j) p[j] = o[j];
    } else {
        int gid = (b - 96) * 256 + t;
        if (gid < 49152) bnst[gid] = 0.f;
        else if (gid < 98304) gout[gid - 49152] = 0.f;
        else if (gid < 98432) gbh[gid - 98304] = 0;
        else if (gid < 98440) ticks[gid - 98432] = 0;
        else if (gid < 98504) hmz[gid - 98440] = 0u;
    }
}

// ---------------- coarse bucket histogram + fused scan (last-block ticket) ----------------
__global__ __launch_bounds__(256) void k_bhist(const int* __restrict__ dst, int* __restrict__ gbh,
                                               int* __restrict__ gbase, int* __restrict__ gcur,
                                               int* __restrict__ row_start, int* __restrict__ tick) {
    __shared__ int lh[128], sbuf[128];
    __shared__ int isLast;
    int t = threadIdx.x;
    if (t < 128) lh[t] = 0;
    __syncthreads();
    for (int e = blockIdx.x * 256 + t; e < NE; e += gridDim.x * 256)
        atomicAdd(&lh[dst[e] >> 10], 1);
    __syncthreads();
    if (t < 128 && lh[t]) atomicAdd(&gbh[t], lh[t]);
    __threadfence();
    __syncthreads();
    if (t == 0) isLast = (atomicAdd(tick, 1) == (int)gridDim.x - 1);
    __syncthreads();
    if (!isLast) return;
    // last block: exclusive scan of the 128 bucket counts
    int v = 0;
    if (t < 128) { v = atomicAdd(&gbh[t], 0); sbuf[t] = v; }
    __syncthreads();
    for (int o = 1; o < 128; o <<= 1) {
        int a = (t >= o && t < 128) ? sbuf[t - o] : 0;
        __syncthreads();
        if (t < 128) sbuf[t] += a;
        __syncthreads();
    }
    if (t < 128) {
        int ex = sbuf[t] - v;
        gbase[t] = ex;
        gcur[t] = ex;
        if (t == 127) { gbase[128] = sbuf[127]; row_start[NN] = NE; }
    }
}

// ---------------- pass 1: bin edges into bucket regions (time-dense writes) ----------------
__global__ __launch_bounds__(256) void k_bin(const int* __restrict__ src, const int* __restrict__ dst,
                                             int* __restrict__ gcur, int* __restrict__ tmp) {
    __shared__ int lh[128], lb[128], lc[128];
    int t = threadIdx.x;
    if (t < 128) lh[t] = 0;
    __syncthreads();
    int e0 = blockIdx.x * BIN_CHUNK, e1 = e0 + BIN_CHUNK;
    for (int e = e0 + t; e < e1; e += 256) atomicAdd(&lh[dst[e] >> 10], 1);
    __syncthreads();
    if (t < 128) {
        int c = lh[t];
        lb[t] = c ? atomicAdd(&gcur[t], c) : 0;
        lc[t] = 0;
    }
    __syncthreads();
    for (int e = e0 + t; e < e1; e += 256) {
        int d = dst[e];
        int b = d >> 10;
        int off = atomicAdd(&lc[b], 1);
        tmp[lb[b] + off] = (src[e] << 10) | (d & 1023);   // src:17b | dst_lo:10b
    }
}

// ---------------- pass 2: per-bucket counting sort -> esrc, row_start, dinv ----------------
__global__ __launch_bounds__(256) void k_csr(const int* __restrict__ tmp, const int* __restrict__ gbase,
                                             int* __restrict__ esrc, int* __restrict__ row_start,
                                             float* __restrict__ dinv) {
    __shared__ int h[1024], hs[1024], part[256];
    int b = blockIdx.x, t = threadIdx.x;
    int base = gbase[b], end = gbase[b + 1];
#pragma unroll
    for (int k = 0; k < 4; ++k) h[t * 4 + k] = 0;
    __syncthreads();
    for (int i = base + t; i < end; i += 256) atomicAdd(&h[tmp[i] & 1023], 1);
    __syncthreads();
    int l0 = h[t * 4], l1 = h[t * 4 + 1], l2 = h[t * 4 + 2], l3 = h[t * 4 + 3];
    int ssum = l0 + l1 + l2 + l3;
    part[t] = ssum;
    __syncthreads();
    for (int o = 1; o < 256; o <<= 1) {
        int a = (t >= o) ? part[t - o] : 0;
        __syncthreads();
        part[t] += a;
        __syncthreads();
    }
    int ex = part[t] - ssum;
    hs[t * 4]     = ex;
    hs[t * 4 + 1] = ex + l0;
    hs[t * 4 + 2] = ex + l0 + l1;
    hs[t * 4 + 3] = ex + l0 + l1 + l2;
    int n0 = b * 1024 + t * 4;
#pragma unroll
    for (int k = 0; k < 4; ++k) {
        int n = n0 + k;
        if (n < NN) {
            row_start[n] = base + hs[t * 4 + k];
            dinv[n] = rsqrtf((float)h[t * 4 + k] + 1.0f);
        }
    }
    __syncthreads();
    for (int i = base + t; i < end; i += 256) {
        int rec = tmp[i];
        int pos = atomicAdd(&hs[rec & 1023], 1);
        esrc[base + pos] = rec >> 10;
    }
}

// ---------------- merged: BN finalize (block 0) + W-scale for next layer (blocks 1..32) ----------------
__global__ __launch_bounds__(128) void k_finwscale(const float* __restrict__ S, const float* __restrict__ Q,
                                                   const float* __restrict__ gam, const float* __restrict__ bet,
                                                   float* __restrict__ svec, float* __restrict__ tvec,
                                                   const float* __restrict__ Wnext, float* __restrict__ tW,
                                                   const ushort* __restrict__ Wfb, ushort* __restrict__ Wff) {
    int bid = blockIdx.x;
    int t = threadIdx.x;
    if (bid == 0) {
        __shared__ float ts[128];
        float s = 0.f, q = 0.f;
        for (int k = 0; k < NBKT; ++k) {
            s += S[k * 128 + t];
            q += Q[k * 128 + t];
        }
        float mean = s / (float)NN;
        float var = q / (float)NN - mean * mean;
        float rstd = rsqrtf(fmaxf(var, 0.f) + BN_EPS);
        float sc = gam[t] * rstd;
        float sh = bet[t] - mean * sc;
        svec[t] = sc;
        tvec[t] = sh;
        ts[t] = sh;
        __syncthreads();
        if (Wnext) {
            float acc = 0.f;
            for (int k = 0; k < 128; ++k) acc += ts[k] * Wnext[(size_t)k * 128 + t];
            tW[t] = acc;
        }
    } else {
        __shared__ float sv[32];
        int unit = bid - 1;
        int kbase = (unit >> 3) * 32;
        if (t < 32) {
            int c = kbase + t;
            float s = 0.f, q = 0.f;
            for (int k = 0; k < NBKT; ++k) {
                s += S[k * 128 + c];
                q += Q[k * 128 + c];
            }
            float mean = s / (float)NN;
            float var = q / (float)NN - mean * mean;
            sv[t] = gam[c] * rsqrtf(fmaxf(var, 0.f) + BN_EPS);
        }
        __syncthreads();
        if (t < 64) {
            int ko = (t >> 4) * 8;   // offset within the 32-k window
            const ushort* p = Wfb + ((size_t)unit * 64 + t) * 8;
            ushort* o = Wff + ((size_t)unit * 64 + t) * 8;
#pragma unroll
            for (int j = 0; j < 8; ++j) o[j] = f2bf(bf2f(p[j]) * sv[ko + j]);
        }
    }
}

// ---------------- MFMA GEMM (pure): hm'[N][128] = dinv[row] * (X @ Wf + tW) ----------------
// X source: xf32 (layer 0, packs fragments in-register) or Xb bf16 (layers 1,2)
__global__ __launch_bounds__(256) void k_gemm(const ushort* __restrict__ Xb, const float* __restrict__ xf32,
                                              const ushort* __restrict__ Wf, const float* __restrict__ tW,
                                              const float* __restrict__ dinv, ushort* __restrict__ hm) {
    int tid = threadIdx.x;
    int wid = tid >> 6, lane = tid & 63;
    int r0 = blockIdx.x * 64 + wid * 16;
    int m = lane & 15, g = lane >> 4;
    int xrow = r0 + m;
    int xr = (xrow < NN) ? xrow : (NN - 1);
    s16x8 af[4];
    if (xf32) {
        const float* Xr = xf32 + (size_t)xr * 128 + g * 8;
#pragma unroll
        for (int ks = 0; ks < 4; ++ks) {
            float4 a = *(const float4*)(Xr + ks * 32);
            float4 b = *(const float4*)(Xr + ks * 32 + 4);
            s16x8 v;
            v[0] = (short)f2bf(a.x); v[1] = (short)f2bf(a.y);
            v[2] = (short)f2bf(a.z); v[3] = (short)f2bf(a.w);
            v[4] = (short)f2bf(b.x); v[5] = (short)f2bf(b.y);
            v[6] = (short)f2bf(b.z); v[7] = (short)f2bf(b.w);
            af[ks] = v;
        }
    } else {
        const ushort* Xrow = Xb + (size_t)xr * 128 + g * 8;
#pragma unroll
        for (int ks = 0; ks < 4; ++ks) af[ks] = *(const s16x8*)(Xrow + ks * 32);
    }
    f32x4 acc[8];
#pragma unroll
    for (int nb = 0; nb < 8; ++nb) acc[nb] = (f32x4){0.f, 0.f, 0.f, 0.f};
#pragma unroll
    for (int ks = 0; ks < 4; ++ks) {
#pragma unroll
        for (int nb = 0; nb < 8; ++nb) {
            s16x8 wf = *(const s16x8*)(Wf + ((size_t)(ks * 8 + nb) * 64 + lane) * 8);
            acc[nb] = __builtin_amdgcn_mfma_f32_16x16x32_bf16(wf, af[ks], acc[nb], 0, 0, 0);
        }
    }
    if (xrow < NN) {
        float ds = dinv[xr];
        ushort* orow = hm + (size_t)xrow * 128 + g * 4;
        if (tW) {
#pragma unroll
            for (int nb = 0; nb < 8; ++nb) {
                float4 tw = *(const float4*)(tW + nb * 16 + g * 4);
                ushort4 o;
                o.x = f2bf(ds * (acc[nb][0] + tw.x));
                o.y = f2bf(ds * (acc[nb][1] + tw.y));
                o.z = f2bf(ds * (acc[nb][2] + tw.z));
                o.w = f2bf(ds * (acc[nb][3] + tw.w));
                *(ushort4*)(orow + nb * 16) = o;
            }
        } else {
#pragma unroll
            for (int nb = 0; nb < 8; ++nb) {
                ushort4 o;
                o.x = f2bf(ds * acc[nb][0]);
                o.y = f2bf(ds * acc[nb][1]);
                o.z = f2bf(ds * acc[nb][2]);
                o.w = f2bf(ds * acc[nb][3]);
                *(ushort4*)(orow + nb * 16) = o;
            }
        }
    }
}

// ---------------- aggregate + bias + relu + fused BN stats (round-10 exact form) ----------------
__global__ __launch_bounds__(256) void k_agg(const uint* __restrict__ hm32, const int* __restrict__ esrc,
                                             const int* __restrict__ rs, const float* __restrict__ dinv,
                                             const float* __restrict__ bias, uint* __restrict__ act,
                                             float* __restrict__ bnsum, float* __restrict__ bnsq) {
    __shared__ float ls[128], lq[128];
    int tid = threadIdx.x;
    if (tid < 128) { ls[tid] = 0.f; lq[tid] = 0.f; }
    __syncthreads();
    int lane = tid & 63;
    int wgid = blockIdx.x * 4 + (tid >> 6);
    float2 b2 = *(const float2*)(bias + lane * 2);
    float s0 = 0.f, s1 = 0.f, q0 = 0.f, q1 = 0.f;

    for (int n = wgid; n < NN; n += AGG_WAVES) {
        uint self = hm32[(size_t)n * 64 + lane];
        float a0 = bf_lo(self);
        float a1 = bf_hi(self);

        int i  = __builtin_amdgcn_readfirstlane(rs[n]);
        int i1 = __builtin_amdgcn_readfirstlane(rs[n + 1]);

        int idxv = 0;
        if (i < i1) idxv = esrc[i + min(min(lane, 15), i1 - i - 1)];

        while (i < i1) {
            int cnt = i1 - i;
            cnt = (cnt > 16) ? 16 : cnt;       // wave-uniform
            int cur = idxv;
            int inext = i + cnt;
            if (inext < i1)                    // prefetch next chunk while gathers fly
                idxv = esrc[inext + min(min(lane, 15), i1 - inext - 1)];
            uint g[16];
#pragma unroll
            for (int u = 0; u < 16; ++u) {
                int sidx = __builtin_amdgcn_readlane(cur, u);
                sidx = (u < cnt) ? sidx : NN;  // scalar select -> zero row for pads
                g[u] = hm32[(size_t)sidx * 64 + lane];
            }
#pragma unroll
            for (int u = 0; u < 16; ++u) {
                a0 += bf_lo(g[u]);
                a1 += bf_hi(g[u]);
            }
            i = inext;
        }
        float di = dinv[n];
        float z0 = fmaxf(fmaf(di, a0, b2.x), 0.f);
        float z1 = fmaxf(fmaf(di, a1, b2.y), 0.f);
        act[(size_t)n * 64 + lane] = packbf(z0, z1);
        s0 += z0; s1 += z1;
        q0 += z0 * z0; q1 += z1 * z1;
    }
    atomicAdd(&ls[lane * 2],     s0);
    atomicAdd(&ls[lane * 2 + 1], s1);
    atomicAdd(&lq[lane * 2],     q0);
    atomicAdd(&lq[lane * 2 + 1], q1);
    __syncthreads();
    if (tid < 128) {
        int bkt = blockIdx.x & (NBKT - 1);
        atomicAdd(&bnsum[bkt * 128 + tid], ls[tid]);
        atomicAdd(&bnsq[bkt * 128 + tid],  lq[tid]);
    }
}

// ---------------- per-graph pool + h_cat out-write ----------------
__global__ __launch_bounds__(128) void k_pool(const uint* __restrict__ act32, const float* __restrict__ svec,
                                              const float* __restrict__ tvec, const int* __restrict__ batch,
                                              float* __restrict__ gout, float* __restrict__ outp, int lofs) {
    int t = threadIdx.x;
    int lane = t & 63;
    int w = t >> 6;
    int n0 = blockIdx.x * 64;
    float sc0 = svec[lane * 2], sc1 = svec[lane * 2 + 1];
    float sh0 = tvec[lane * 2], sh1 = tvec[lane * 2 + 1];
    float s0 = 0.f, s1 = 0.f;
    int cnt = 0, curg = -1;
    for (int k = w; k < 64; k += 2) {
        int n = n0 + k;
        if (n >= NN) break;
        int gn = batch[n];
        if (gn != curg) {
            if (cnt) {
                atomicAdd(&gout[(size_t)curg * 384 + lofs + lane * 2],     sc0 * s0 + sh0 * (float)cnt);
                atomicAdd(&gout[(size_t)curg * 384 + lofs + lane * 2 + 1], sc1 * s1 + sh1 * (float)cnt);
            }
            curg = gn; s0 = 0.f; s1 = 0.f; cnt = 0;
        }
        uint v = act32[(size_t)n * 64 + lane];
        float a0 = bf_lo(v), a1 = bf_hi(v);
        float2 z;
        z.x = a0 * sc0 + sh0;
        z.y = a1 * sc1 + sh1;
        *(float2*)(outp + (size_t)n * 384 + lofs + lane * 2) = z;
        s0 += a0;
        s1 += a1;
        ++cnt;
    }
    if (cnt) {
        atomicAdd(&gout[(size_t)curg * 384 + lofs + lane * 2],     sc0 * s0 + sh0 * (float)cnt);
        atomicAdd(&gout[(size_t)curg * 384 + lofs + lane * 2 + 1], sc1 * s1 + sh1 * (float)cnt);
    }
}

extern "C" void kernel_launch(void* const* d_in, const int* in_sizes, int n_in,
                              void* d_out, int out_size, void* d_ws, size_t ws_size,
                              hipStream_t stream) {
    const float* x = (const float*)d_in[0];
    const int* ei = (const int*)d_in[1];
    const int* src = ei;
    const int* dst = ei + NE;
    const int* batch = (const int*)d_in[2];
    const float *W[3], *b[3], *g[3], *beta[3];
    for (int l = 0; l < 3; ++l) {
        W[l]    = (const float*)d_in[3 + 4 * l];
        b[l]    = (const float*)d_in[4 + 4 * l];
        g[l]    = (const float*)d_in[5 + 4 * l];
        beta[l] = (const float*)d_in[6 + 4 * l];
    }
    float* out = (float*)d_out;
    float* gout = out + (size_t)NN * 384;

    char* ws = (char*)d_ws;
    size_t off = 0;
    auto alloc = [&](size_t bytes) -> char* {
        off = (off + 255) & ~(size_t)255;
        char* p = ws + off;
        off += bytes;
        return p;
    };
    ushort* act      = (ushort*)alloc((size_t)NN * 256);        // bf16 relu output (pre-BN)
    ushort* hm       = (ushort*)alloc((size_t)(NN + 1) * 256);  // bf16 hm' rows + zero row at NN
    int*    esrc     = (int*)alloc((size_t)NE * 4);
    int*    tmp      = (int*)alloc((size_t)NE * 4);
    int*    row_start= (int*)alloc((size_t)(NN + 1) * 4);
    float*  dinv     = (float*)alloc((size_t)NN * 4);
    float*  bnst     = (float*)alloc((size_t)3 * 2 * NBKT * 128 * 4);   // [layer][sum|sq][NBKT][128]
    ushort* Wf       = (ushort*)alloc(3 * 16384 * 2);
    ushort* Wff      = (ushort*)alloc(16384 * 2);
    float*  svt      = (float*)alloc(3 * 2 * 128 * 4);                  // [layer][s|t][128]
    float*  tW       = (float*)alloc(128 * 4);
    int*    misc     = (int*)alloc(1024 * 4);   // gbh[128], gbase[129], gcur[128], ticks[8]
    int* gbh   = misc;
    int* gbase = misc + 128;
    int* gcur  = misc + 384;
    int* ticks = misc + 512;
    uint* hmz  = (uint*)(hm + (size_t)NN * 128);
    (void)ws_size;

    // 16 dispatches, no memsets
    k_setup<<<481, 256, 0, stream>>>(W[0], W[1], W[2], Wf, gbh, ticks, bnst, gout, hmz);
    k_bhist<<<512, 256, 0, stream>>>(dst, gbh, gbase, gcur, row_start, ticks);
    k_bin<<<BIN_BLOCKS, 256, 0, stream>>>(src, dst, gcur, tmp);
    k_csr<<<NBUCK, 256, 0, stream>>>(tmp, gbase, esrc, row_start, dinv);

    for (int l = 0; l < 3; ++l) {
        float* S = bnst + (size_t)l * 2 * NBKT * 128;
        float* Q = S + NBKT * 128;
        float* sv = svt + l * 256;
        float* tv = sv + 128;
        const ushort* gin = (l == 0) ? (const ushort*)nullptr : act;
        const float* xin = (l == 0) ? x : nullptr;
        const ushort* wfrag = (l == 0) ? (Wf + 0) : Wff;
        const float* tw_in = (l == 0) ? nullptr : tW;
        const float* wnp = (l < 2) ? W[l + 1] : nullptr;
        const ushort* wfbp = (l < 2) ? (Wf + (size_t)(l + 1) * 16384) : nullptr;

        k_gemm<<<(NN + 63) / 64, 256, 0, stream>>>(gin, xin, wfrag, tw_in, dinv, hm);
        k_agg<<<AGG_BLOCKS, 256, 0, stream>>>((const uint*)hm, esrc, row_start, dinv, b[l],
                                              (uint*)act, S, Q);
        k_finwscale<<<(l < 2) ? 33 : 1, 128, 0, stream>>>(S, Q, g[l], beta[l], sv, tv,
                                                          wnp, tW, wfbp, Wff);
        k_pool<<<(NN + 63) / 64, 128, 0, stream>>>((const uint*)act, sv, tv, batch, gout, out, l * 128);
    }
}